// Round 6
// baseline (216.314 us; speedup 1.0000x reference)
//
#include <hip/hip_runtime.h>

#define BB 2
#define NPTS 16384
#define NQ (2*BB*NPTS)        // 65536 query work-items (2 directions x B x N)

typedef float f32x2 __attribute__((ext_vector_type(2)));

// ---- packed fp32 helpers (VOP3P, gfx90a+/gfx950). Each half rounds exactly
// like the scalar op, so results are bitwise equal to the scalar chain. ----
__device__ __forceinline__ f32x2 pk_mul_blo(f32x2 a, f32x2 b) {   // (a.lo*b.lo, a.hi*b.lo)
    f32x2 d;
    asm("v_pk_mul_f32 %0, %1, %2 op_sel:[0,0] op_sel_hi:[1,0]" : "=v"(d) : "v"(a), "v"(b));
    return d;
}
__device__ __forceinline__ f32x2 pk_fma_bhi(f32x2 a, f32x2 b, f32x2 c) { // (fma(a.lo,b.hi,c.lo), fma(a.hi,b.hi,c.hi))
    f32x2 d;
    asm("v_pk_fma_f32 %0, %1, %2, %3 op_sel:[0,1,0] op_sel_hi:[1,1,1]" : "=v"(d) : "v"(a), "v"(b), "v"(c));
    return d;
}
__device__ __forceinline__ f32x2 pk_fma_blo(f32x2 a, f32x2 b, f32x2 c) { // (fma(a.lo,b.lo,c.lo), fma(a.hi,b.lo,c.hi))
    f32x2 d;
    asm("v_pk_fma_f32 %0, %1, %2, %3 op_sel:[0,0,0] op_sel_hi:[1,0,1]" : "=v"(d) : "v"(a), "v"(b), "v"(c));
    return d;
}
__device__ __forceinline__ f32x2 pk_add_bhi(f32x2 a, f32x2 b) {   // (a.lo+b.hi, a.hi+b.hi)
    f32x2 d;
    asm("v_pk_add_f32 %0, %1, %2 op_sel:[0,1] op_sel_hi:[1,1]" : "=v"(d) : "v"(a), "v"(b));
    return d;
}
__device__ __forceinline__ f32x2 pk_fma_pk(f32x2 a, f32x2 b, f32x2 c) {  // natural packed fma
    f32x2 d;
    asm("v_pk_fma_f32 %0, %1, %2, %3" : "=v"(d) : "v"(a), "v"(b), "v"(c));
    return d;
}

// ws layout (CH = CHUNKS):
//   float4 cand[2][BB][NPTS]   : 1 MB  (slot 0: xyz2 points, slot 1: xyz1 points; w = |p|^2)
//   float  pd[CH][NQ]          : CH*256 KB   (min distance per chunk, round-2-exact key)
//   int    pi[CH][NQ]          : CH*256 KB   (argmin per chunk, global candidate index)

__global__ __launch_bounds__(256) void prep_kernel(
    const float* __restrict__ xyz1, const float* __restrict__ xyz2,
    float4* __restrict__ cand)
{
    int t = blockIdx.x * 256 + threadIdx.x;   // 0..65535
    int dir = t >> 15;                        // 0: xyz2 points, 1: xyz1 points
    int rem = t & 32767;                      // b*NPTS + j
    const float* src = dir ? xyz1 : xyz2;
    float x = src[rem*3+0];
    float y = src[rem*3+1];
    float z = src[rem*3+2];
    // match numpy sum(b*b,-1): (x*x + y*y) + z*z, no contraction
    float sq = __fadd_rn(__fadd_rn(__fmul_rn(x,x), __fmul_rn(y,y)), __fmul_rn(z,z));
    cand[t] = make_float4(x, y, z, sq);
}

// 4 queries per thread packed as 2 f32x2 pairs; candidates broadcast via op_sel.
// Key is bit-exact to round 2: t = fma(az,cz, fma(ay,cy, ax*cx)); d = fma(-2,t, rn(asq+bsq)).
// Group-min (G=32) + rescan argmin. Grid: (64, CH).
template<int CH>
__global__ __launch_bounds__(256) void nn_partial4pk(
    const float4* __restrict__ cand,
    float* __restrict__ pd, int* __restrict__ pi)
{
    constexpr int CLEN = NPTS / CH;
    constexpr int G    = 32;
    constexpr int NGRP = CLEN / G;
    const int bx    = blockIdx.x;          // 0..63
    const int chunk = blockIdx.y;          // 0..CH-1
    const int dir   = bx >> 5;             // 32 blocks per direction
    const int q15b  = (bx & 31) << 10;     // within-direction query base (1024-aligned)
    const int bb    = (q15b >> 14) & 1;    // batch index

    const float4* qt  = cand + ((dir ^ 1) << 15) + q15b;                 // queries
    const float4* cp4 = cand + (dir << 15) + (bb << 14) + chunk * CLEN;  // candidates
    const f32x2*  cp2 = (const f32x2*)cp4;

    const int t = threadIdx.x;

    // Query packs: pack p holds queries (2p, 2p+1); X=(ax_lo,ax_hi) etc.
    f32x2 X[2], Y[2], Z[2], W[2];
    #pragma unroll
    for (int p = 0; p < 2; ++p) {
        float4 q0 = qt[t + (2*p+0)*256];
        float4 q1 = qt[t + (2*p+1)*256];
        X[p].x = q0.x; X[p].y = q1.x;
        Y[p].x = q0.y; Y[p].y = q1.y;
        Z[p].x = q0.z; Z[p].y = q1.z;
        W[p].x = q0.w; W[p].y = q1.w;
    }
    f32x2 m2; m2.x = -2.0f; m2.y = -2.0f;

    float bd[4]; int gbest[4];
    #pragma unroll
    for (int k = 0; k < 4; ++k) { bd[k] = __builtin_inff(); gbest[k] = 0; }

    for (int g = 0; g < NGRP; ++g) {
        f32x2 gacc[2];
        gacc[0].x = __builtin_inff(); gacc[0].y = __builtin_inff();
        gacc[1].x = __builtin_inff(); gacc[1].y = __builtin_inff();
        #pragma unroll 2
        for (int j = 0; j < G; j += 2) {
            // candidate c = (P=(cx,cy), Q=(cz,cw)) as two natural VGPR pairs
            f32x2 P0 = cp2[(g*G + j)*2 + 0];
            f32x2 Q0 = cp2[(g*G + j)*2 + 1];
            f32x2 P1 = cp2[(g*G + j)*2 + 2];
            f32x2 Q1 = cp2[(g*G + j)*2 + 3];
            #pragma unroll
            for (int p = 0; p < 2; ++p) {
                f32x2 t0 = pk_mul_blo(X[p], P0);        // ax*cx
                t0 = pk_fma_bhi(Y[p], P0, t0);          // + ay*cy
                t0 = pk_fma_blo(Z[p], Q0, t0);          // + az*cz
                f32x2 s0 = pk_add_bhi(W[p], Q0);        // asq + bsq
                f32x2 d0 = pk_fma_pk(m2, t0, s0);       // -2*t + s

                f32x2 t1 = pk_mul_blo(X[p], P1);
                t1 = pk_fma_bhi(Y[p], P1, t1);
                t1 = pk_fma_blo(Z[p], Q1, t1);
                f32x2 s1 = pk_add_bhi(W[p], Q1);
                f32x2 d1 = pk_fma_pk(m2, t1, s1);

                // v_min3-fusable; fminf returns an input bitwise
                gacc[p].x = fminf(fminf(d0.x, d1.x), gacc[p].x);
                gacc[p].y = fminf(fminf(d0.y, d1.y), gacc[p].y);
            }
        }
        float ga[4] = {gacc[0].x, gacc[0].y, gacc[1].x, gacc[1].y};
        #pragma unroll
        for (int k = 0; k < 4; ++k) {
            bool imp = ga[k] < bd[k];            // strict: earlier group wins ties
            bd[k]    = imp ? ga[k] : bd[k];
            gbest[k] = imp ? g     : gbest[k];
        }
    }

    // Rescan winning group with the identical scalar chain (bitwise == pk halves).
    const int qid0 = (dir << 15) + q15b + t;
    #pragma unroll
    for (int k = 0; k < 4; ++k) {
        float axk = (k & 1) ? X[k>>1].y : X[k>>1].x;
        float ayk = (k & 1) ? Y[k>>1].y : Y[k>>1].x;
        float azk = (k & 1) ? Z[k>>1].y : Z[k>>1].x;
        float awk = (k & 1) ? W[k>>1].y : W[k>>1].x;
        const float4* rp = cp4 + gbest[k] * G;
        int idx = 0;
        #pragma unroll 4
        for (int j = G - 1; j >= 0; --j) {       // backward: last update = first match
            float4 c = rp[j];
            float tt = fmaf(azk, c.z, fmaf(ayk, c.y, __fmul_rn(axk, c.x)));
            float dd = fmaf(-2.0f, tt, __fadd_rn(awk, c.w));
            idx = (dd != bd[k]) ? idx : j;
        }
        int qid = qid0 + k*256;
        pd[chunk*NQ + qid] = bd[k];
        pi[chunk*NQ + qid] = chunk*CLEN + gbest[k]*G + idx;
    }
}

template<int CH>
__global__ __launch_bounds__(256) void nn_merge(
    const float* __restrict__ pd, const int* __restrict__ pi,
    float* __restrict__ out)
{
    int qid = blockIdx.x * 256 + threadIdx.x;
    float bd = pd[qid];
    int   bi = pi[qid];
    #pragma unroll
    for (int c = 1; c < CH; ++c) {
        float d = pd[c*NQ + qid];
        int   i = pi[c*NQ + qid];
        if (d < bd || (d == bd && i < bi)) { bd = d; bi = i; }  // lower index wins ties
    }
    int dir = qid >> 15;
    int q15 = qid & 32767;
    // out: [dist1 (32768) | dist2 (32768) | idx1 (32768) | idx2 (32768)]
    int off = dir ? 32768 : 0;
    out[off + q15]         = bd;
    out[65536 + off + q15] = (float)bi;
}

// Ultimate fallback (no ws): fused, recomputes bsq in-loop.
__global__ __launch_bounds__(256) void nn_full(
    const float* __restrict__ xyz1, const float* __restrict__ xyz2,
    float* __restrict__ out)
{
    int qid = blockIdx.x * 256 + threadIdx.x;
    int dir = qid >> 15;
    int q15 = qid & 32767;
    const float* qsrc = dir ? xyz2 : xyz1;
    float ax = qsrc[q15*3+0];
    float ay = qsrc[q15*3+1];
    float az = qsrc[q15*3+2];
    float asq = __fadd_rn(__fadd_rn(__fmul_rn(ax,ax), __fmul_rn(ay,ay)), __fmul_rn(az,az));
    const float* cp = (dir ? xyz1 : xyz2) + (size_t)(q15 & NPTS) * 3;

    float bd = 3.402823466e+38f; int bi = 0;
    for (int j = 0; j < NPTS; ++j) {
        float bx = cp[3*j+0], by = cp[3*j+1], bz = cp[3*j+2];
        float bsq = __fadd_rn(__fadd_rn(__fmul_rn(bx,bx), __fmul_rn(by,by)), __fmul_rn(bz,bz));
        float tt = fmaf(az, bz, fmaf(ay, by, __fmul_rn(ax, bx)));
        float d = fmaf(-2.0f, tt, __fadd_rn(asq, bsq));
        if (d < bd) { bd = d; bi = j; }
    }
    int off = dir ? 32768 : 0;
    out[off + q15]         = bd;
    out[65536 + off + q15] = (float)bi;
}

extern "C" void kernel_launch(void* const* d_in, const int* in_sizes, int n_in,
                              void* d_out, int out_size, void* d_ws, size_t ws_size,
                              hipStream_t stream) {
    const float* xyz1 = (const float*)d_in[0];
    const float* xyz2 = (const float*)d_in[1];
    float* out = (float*)d_out;

    size_t cand_bytes = (size_t)NQ * 16;  // 1 MB

    auto run = [&](auto ch_const) {
        constexpr int CH = decltype(ch_const)::value;
        float4* cand = (float4*)d_ws;
        float*  pd   = (float*)((char*)d_ws + cand_bytes);
        int*    pi   = (int*)((char*)d_ws + cand_bytes + (size_t)CH*NQ*4);
        prep_kernel<<<NQ/256, 256, 0, stream>>>(xyz1, xyz2, cand);
        dim3 grid(64, CH);
        nn_partial4pk<CH><<<grid, 256, 0, stream>>>(cand, pd, pi);
        nn_merge<CH><<<NQ/256, 256, 0, stream>>>(pd, pi, out);
    };

    size_t need32 = cand_bytes + (size_t)32*NQ*8;  // 17 MB
    size_t need8  = cand_bytes + (size_t)8*NQ*8;   // 5 MB
    if (d_ws != nullptr && ws_size >= need32) {
        run(std::integral_constant<int, 32>{});
    } else if (d_ws != nullptr && ws_size >= need8) {
        run(std::integral_constant<int, 8>{});
    } else {
        nn_full<<<NQ/256, 256, 0, stream>>>(xyz1, xyz2, out);
    }
}